// Round 1
// baseline (7727.288 us; speedup 1.0000x reference)
//
#include <hip/hip_runtime.h>
#include <hip/hip_bf16.h>
#include <math.h>

// ---------------------------------------------------------------------------
// GIN encoder: 3 x [ (1+eps)h + scatter_add(h[col] -> row) ; Linear ; BN ;
//                    ReLU ; Linear ; BN ; (inter-layer ReLU) ]
// fp32 throughout (round 1: correctness + profiling baseline).
// ---------------------------------------------------------------------------

__global__ void zero_kernel(float* __restrict__ p, int n) {
    int i = blockIdx.x * blockDim.x + threadIdx.x;
    if (i < n) p[i] = 0.f;
}

// out = (1+eps[layer]) * h   (float4 elementwise)
__global__ void init_scaled(const float4* __restrict__ h, const float* __restrict__ eps,
                            int layer, float4* __restrict__ out, int total4) {
    int i = blockIdx.x * blockDim.x + threadIdx.x;
    if (i >= total4) return;
    float s = 1.f + eps[layer];
    float4 v = h[i];
    v.x *= s; v.y *= s; v.z *= s; v.w *= s;
    out[i] = v;
}

// agg[row[e]] += h[col[e]] ; one (H/4)-lane group per edge, float4 gather + 4 scalar atomics
template<int H>
__global__ void scatter_add_k(const float* __restrict__ h, const int* __restrict__ rowi,
                              const int* __restrict__ coli, float* __restrict__ agg, int E) {
    constexpr int TPE = H / 4;        // threads per edge
    constexpr int EPB = 256 / TPE;    // edges per block
    int e = blockIdx.x * EPB + threadIdx.x / TPE;
    if (e >= E) return;
    int lane = threadIdx.x % TPE;
    int r = rowi[e];
    int c = coli[e];
    const float4* src = (const float4*)(h + (size_t)c * H);
    float4 v = src[lane];
    float* dst = agg + (size_t)r * H + lane * 4;
    atomicAdd(dst + 0, v.x);
    atomicAdd(dst + 1, v.y);
    atomicAdd(dst + 2, v.z);
    atomicAdd(dst + 3, v.w);
}

// Y[N x 256] = A[N x K] @ W[K x 256] + bias ; 64x64 tile, 4x4 per thread, K-chunks of 32
template<int K>
__global__ __launch_bounds__(256) void gemm_bias(const float* __restrict__ A,
                                                 const float* __restrict__ W,
                                                 const float* __restrict__ bias,
                                                 float* __restrict__ Y, int Nrows) {
    __shared__ float aT[32][68];   // aT[k][r], pad 68 keeps float4 alignment + spreads banks
    __shared__ float wS[32][68];   // wS[k][c]
    const int tid = threadIdx.x;
    const int r0 = blockIdx.x * 64;
    const int c0 = blockIdx.y * 64;
    const int tr = (tid >> 4) * 4;   // 0..60
    const int tc = (tid & 15) * 4;   // 0..60
    const int kk_l = tid & 31;
    const int rb   = tid >> 5;       // 0..7
    const int cc_l = tid & 63;
    const int kb   = tid >> 6;       // 0..3

    float acc[4][4] = {};

    for (int k0 = 0; k0 < K; k0 += 32) {
        // stage A-tile transposed: aT[kk][r] = A[r0+r][k0+kk]
#pragma unroll
        for (int j = 0; j < 8; ++j) {
            int r = rb + 8 * j;
            int gr = r0 + r;
            aT[kk_l][r] = (gr < Nrows) ? A[(size_t)gr * K + k0 + kk_l] : 0.f;
        }
        // stage W-tile: wS[kk][c] = W[k0+kk][c0+c]
#pragma unroll
        for (int j = 0; j < 8; ++j) {
            int kk = kb + 4 * j;
            wS[kk][cc_l] = W[(size_t)(k0 + kk) * 256 + c0 + cc_l];
        }
        __syncthreads();
#pragma unroll
        for (int kk = 0; kk < 32; ++kk) {
            float4 a = *(const float4*)&aT[kk][tr];
            float4 w = *(const float4*)&wS[kk][tc];
            acc[0][0] += a.x * w.x; acc[0][1] += a.x * w.y; acc[0][2] += a.x * w.z; acc[0][3] += a.x * w.w;
            acc[1][0] += a.y * w.x; acc[1][1] += a.y * w.y; acc[1][2] += a.y * w.z; acc[1][3] += a.y * w.w;
            acc[2][0] += a.z * w.x; acc[2][1] += a.z * w.y; acc[2][2] += a.z * w.z; acc[2][3] += a.z * w.w;
            acc[3][0] += a.w * w.x; acc[3][1] += a.w * w.y; acc[3][2] += a.w * w.z; acc[3][3] += a.w * w.w;
        }
        __syncthreads();
    }

    float4 bv = *(const float4*)&bias[c0 + tc];
#pragma unroll
    for (int i2 = 0; i2 < 4; ++i2) {
        int gr = r0 + tr + i2;
        if (gr < Nrows) {
            float4 o;
            o.x = acc[i2][0] + bv.x;
            o.y = acc[i2][1] + bv.y;
            o.z = acc[i2][2] + bv.z;
            o.w = acc[i2][3] + bv.w;
            *(float4*)&Y[(size_t)gr * 256 + c0 + tc] = o;
        }
    }
}

// column sums + sumsq over rows (256 cols fixed); block = 256 rows strip
__global__ void colstats(const float* __restrict__ Y, float* __restrict__ stats, int Nrows) {
    int c = threadIdx.x;
    int r0 = blockIdx.x * 256;
    int rend = min(r0 + 256, Nrows);
    float s = 0.f, sq = 0.f;
    for (int r = r0; r < rend; ++r) {
        float v = Y[(size_t)r * 256 + c];
        s += v;
        sq += v * v;
    }
    atomicAdd(&stats[c], s);
    atomicAdd(&stats[256 + c], sq);
}

// scale/shift from stats: scale = g*rsqrt(var+eps), shift = bt - mean*scale
__global__ void bnparams(const float* __restrict__ stats, const float* __restrict__ g,
                         const float* __restrict__ bt, float* __restrict__ params, float invN) {
    int c = threadIdx.x;
    float mean = stats[c] * invN;
    float var = stats[256 + c] * invN - mean * mean;
    float scale = g[c] * rsqrtf(var + 1e-5f);
    params[c] = scale;
    params[256 + c] = bt[c] - mean * scale;
}

// out = (relu?) (Y*scale + shift)   per-column params, float4
__global__ void bn_apply(const float4* __restrict__ Y, const float* __restrict__ params,
                         float4* __restrict__ out, int total4, int relu) {
    int i = blockIdx.x * blockDim.x + threadIdx.x;
    if (i >= total4) return;
    int cq = i & 63;  // column-quad index (256 cols / 4)
    float4 sc = ((const float4*)params)[cq];
    float4 sh = ((const float4*)(params + 256))[cq];
    float4 y = Y[i];
    float4 o;
    o.x = y.x * sc.x + sh.x;
    o.y = y.y * sc.y + sh.y;
    o.z = y.z * sc.z + sh.z;
    o.w = y.w * sc.w + sh.w;
    if (relu) {
        o.x = fmaxf(o.x, 0.f);
        o.y = fmaxf(o.y, 0.f);
        o.z = fmaxf(o.z, 0.f);
        o.w = fmaxf(o.w, 0.f);
    }
    out[i] = o;
}

extern "C" void kernel_launch(void* const* d_in, const int* in_sizes, int n_in,
                              void* d_out, int out_size, void* d_ws, size_t ws_size,
                              hipStream_t stream) {
    const float* x      = (const float*)d_in[0];
    const int*   ei     = (const int*)d_in[1];
    const float* eps    = (const float*)d_in[2];
    const float* W1_0   = (const float*)d_in[3];
    const float* W1rest = (const float*)d_in[4];
    const float* b1     = (const float*)d_in[5];
    const float* g1     = (const float*)d_in[6];
    const float* bt1    = (const float*)d_in[7];
    const float* W2     = (const float*)d_in[8];
    const float* b2     = (const float*)d_in[9];
    const float* g2     = (const float*)d_in[10];
    const float* bt2    = (const float*)d_in[11];

    const int N = in_sizes[0] / 128;
    const int E = in_sizes[1] / 2;
    const int* row = ei;
    const int* col = ei + E;

    float* out  = (float*)d_out;           // N x 256, also inter-layer h buffer
    float* bufA = (float*)d_ws;            // N x 256
    float* bufY = bufA + (size_t)N * 256;  // N x 256
    float* stats  = bufY + (size_t)N * 256;  // 6 * 512
    float* params = stats + 6 * 512;         // 6 * 512

    const float invN = 1.f / (float)N;

    zero_kernel<<<(6 * 512 + 255) / 256, 256, 0, stream>>>(stats, 6 * 512);

    const float* h = x;
    for (int layer = 0; layer < 3; ++layer) {
        const int Hin = (layer == 0) ? 128 : 256;
        const int total4_in = N * Hin / 4;
        const int total4 = N * 256 / 4;

        // bufA = (1+eps)*h ; then += scatter of neighbors
        init_scaled<<<(total4_in + 255) / 256, 256, 0, stream>>>(
            (const float4*)h, eps, layer, (float4*)bufA, total4_in);
        if (Hin == 128)
            scatter_add_k<128><<<(E + 7) / 8, 256, 0, stream>>>(h, row, col, bufA, E);
        else
            scatter_add_k<256><<<(E + 3) / 4, 256, 0, stream>>>(h, row, col, bufA, E);

        // Linear 1
        const float* Wa = (layer == 0) ? W1_0 : (W1rest + (size_t)(layer - 1) * 256 * 256);
        dim3 gg((N + 63) / 64, 4);
        if (Hin == 128)
            gemm_bias<128><<<gg, 256, 0, stream>>>(bufA, Wa, b1 + layer * 256, bufY, N);
        else
            gemm_bias<256><<<gg, 256, 0, stream>>>(bufA, Wa, b1 + layer * 256, bufY, N);

        // BN 1 + ReLU -> bufA
        float* st1 = stats + layer * 1024;
        float* pr1 = params + layer * 1024;
        colstats<<<(N + 255) / 256, 256, 0, stream>>>(bufY, st1, N);
        bnparams<<<1, 256, 0, stream>>>(st1, g1 + layer * 256, bt1 + layer * 256, pr1, invN);
        bn_apply<<<(total4 + 255) / 256, 256, 0, stream>>>(
            (const float4*)bufY, pr1, (float4*)bufA, total4, 1);

        // Linear 2
        gemm_bias<256><<<gg, 256, 0, stream>>>(bufA, W2 + (size_t)layer * 256 * 256,
                                               b2 + layer * 256, bufY, N);

        // BN 2 (+ inter-layer ReLU) -> out
        float* st2 = st1 + 512;
        float* pr2 = pr1 + 512;
        colstats<<<(N + 255) / 256, 256, 0, stream>>>(bufY, st2, N);
        bnparams<<<1, 256, 0, stream>>>(st2, g2 + layer * 256, bt2 + layer * 256, pr2, invN);
        bn_apply<<<(total4 + 255) / 256, 256, 0, stream>>>(
            (const float4*)bufY, pr2, (float4*)out, total4, (layer < 2) ? 1 : 0);

        h = out;
    }
}

// Round 2
// 1420.519 us; speedup vs baseline: 5.4398x; 5.4398x over previous
//
#include <hip/hip_runtime.h>
#include <hip/hip_bf16.h>
#include <math.h>

// ---------------------------------------------------------------------------
// GIN encoder. R2: replace per-edge float atomics (3.2GB HBM write-through,
// ~6.6ms) with per-call CSR build + pull-style per-node aggregation.
// ---------------------------------------------------------------------------

__global__ void zero_f(float* __restrict__ p, int n) {
    int i = blockIdx.x * blockDim.x + threadIdx.x;
    if (i < n) p[i] = 0.f;
}
__global__ void zero_i(int* __restrict__ p, int n) {
    int i = blockIdx.x * blockDim.x + threadIdx.x;
    if (i < n) p[i] = 0;
}

// ---- CSR build ----
__global__ void hist_k(const int* __restrict__ row, int* __restrict__ deg, int E) {
    int e = blockIdx.x * blockDim.x + threadIdx.x;
    if (e < E) atomicAdd(&deg[row[e]], 1);
}

// per-256-block sums of deg
__global__ void block_sums(const int* __restrict__ deg, int* __restrict__ bs, int N) {
    __shared__ int tmp[256];
    int t = threadIdx.x;
    int i = blockIdx.x * 256 + t;
    tmp[t] = (i < N) ? deg[i] : 0;
    __syncthreads();
    for (int off = 128; off > 0; off >>= 1) {
        if (t < off) tmp[t] += tmp[t + off];
        __syncthreads();
    }
    if (t == 0) bs[blockIdx.x] = tmp[0];
}

// exclusive scan of block sums (B <= 256), single block
__global__ void scan_bs(const int* __restrict__ bs, int* __restrict__ bo, int B) {
    __shared__ int tmp[256];
    int t = threadIdx.x;
    int v = (t < B) ? bs[t] : 0;
    tmp[t] = v;
    __syncthreads();
    for (int off = 1; off < 256; off <<= 1) {
        int x = (t >= off) ? tmp[t - off] : 0;
        __syncthreads();
        tmp[t] += x;
        __syncthreads();
    }
    bo[t] = tmp[t] - v;  // exclusive
}

// rowptr[i] = bo[blk] + exclusive-scan-within-block(deg); cursor copy; rowptr[N]=E
__global__ void finalize_rowptr(const int* __restrict__ deg, const int* __restrict__ bo,
                                int* __restrict__ rowptr, int* __restrict__ cursor,
                                int N, int E) {
    __shared__ int tmp[256];
    int t = threadIdx.x;
    int i = blockIdx.x * 256 + t;
    int v = (i < N) ? deg[i] : 0;
    tmp[t] = v;
    __syncthreads();
    for (int off = 1; off < 256; off <<= 1) {
        int x = (t >= off) ? tmp[t - off] : 0;
        __syncthreads();
        tmp[t] += x;
        __syncthreads();
    }
    int excl = tmp[t] - v + bo[blockIdx.x];
    if (i < N) { rowptr[i] = excl; cursor[i] = excl; }
    if (i == N) rowptr[N] = E;
}

__global__ void fill_csr(const int* __restrict__ row, const int* __restrict__ col,
                         int* __restrict__ cursor, int* __restrict__ idx, int E) {
    int e = blockIdx.x * blockDim.x + threadIdx.x;
    if (e < E) {
        int p = atomicAdd(&cursor[row[e]], 1);
        idx[p] = col[e];
    }
}

// ---- pull aggregation: out[v] = (1+eps)*h[v] + sum_{u in N(v)} h[u] ----
// one 64-lane wave per node; 4 waves per block.
template<int H>
__global__ __launch_bounds__(256) void aggregate(const float* __restrict__ h,
                                                 const int* __restrict__ rowptr,
                                                 const int* __restrict__ idx,
                                                 const float* __restrict__ eps, int layer,
                                                 float* __restrict__ out, int N) {
    constexpr int VW = H / 64;  // floats per lane (2 or 4)
    int lane = threadIdx.x & 63;
    int v = blockIdx.x * 4 + (threadIdx.x >> 6);
    if (v >= N) return;
    float s = 1.f + eps[layer];

    float acc[VW];
    {
        const float* hv = h + (size_t)v * H + lane * VW;
#pragma unroll
        for (int j = 0; j < VW; ++j) acc[j] = s * hv[j];
    }

    int e = rowptr[v];
    int end = rowptr[v + 1];
    // 2-edge unroll for a bit of MLP
    for (; e + 1 < end; e += 2) {
        int u0 = idx[e], u1 = idx[e + 1];
        const float* h0 = h + (size_t)u0 * H + lane * VW;
        const float* h1 = h + (size_t)u1 * H + lane * VW;
        float t0[VW], t1[VW];
#pragma unroll
        for (int j = 0; j < VW; ++j) t0[j] = h0[j];
#pragma unroll
        for (int j = 0; j < VW; ++j) t1[j] = h1[j];
#pragma unroll
        for (int j = 0; j < VW; ++j) acc[j] += t0[j] + t1[j];
    }
    if (e < end) {
        int u = idx[e];
        const float* hu = h + (size_t)u * H + lane * VW;
#pragma unroll
        for (int j = 0; j < VW; ++j) acc[j] += hu[j];
    }

    float* ov = out + (size_t)v * H + lane * VW;
#pragma unroll
    for (int j = 0; j < VW; ++j) ov[j] = acc[j];
}

// ---- GEMM: Y[N x 256] = A[N x K] @ W[K x 256] + bias ----
template<int K>
__global__ __launch_bounds__(256) void gemm_bias(const float* __restrict__ A,
                                                 const float* __restrict__ W,
                                                 const float* __restrict__ bias,
                                                 float* __restrict__ Y, int Nrows) {
    __shared__ float aT[32][68];
    __shared__ float wS[32][68];
    const int tid = threadIdx.x;
    const int r0 = blockIdx.x * 64;
    const int c0 = blockIdx.y * 64;
    const int tr = (tid >> 4) * 4;
    const int tc = (tid & 15) * 4;
    const int kk_l = tid & 31;
    const int rb   = tid >> 5;
    const int cc_l = tid & 63;
    const int kb   = tid >> 6;

    float acc[4][4] = {};

    for (int k0 = 0; k0 < K; k0 += 32) {
#pragma unroll
        for (int j = 0; j < 8; ++j) {
            int r = rb + 8 * j;
            int gr = r0 + r;
            aT[kk_l][r] = (gr < Nrows) ? A[(size_t)gr * K + k0 + kk_l] : 0.f;
        }
#pragma unroll
        for (int j = 0; j < 8; ++j) {
            int kk = kb + 4 * j;
            wS[kk][cc_l] = W[(size_t)(k0 + kk) * 256 + c0 + cc_l];
        }
        __syncthreads();
#pragma unroll
        for (int kk = 0; kk < 32; ++kk) {
            float4 a = *(const float4*)&aT[kk][tr];
            float4 w = *(const float4*)&wS[kk][tc];
            acc[0][0] += a.x * w.x; acc[0][1] += a.x * w.y; acc[0][2] += a.x * w.z; acc[0][3] += a.x * w.w;
            acc[1][0] += a.y * w.x; acc[1][1] += a.y * w.y; acc[1][2] += a.y * w.z; acc[1][3] += a.y * w.w;
            acc[2][0] += a.z * w.x; acc[2][1] += a.z * w.y; acc[2][2] += a.z * w.z; acc[2][3] += a.z * w.w;
            acc[3][0] += a.w * w.x; acc[3][1] += a.w * w.y; acc[3][2] += a.w * w.z; acc[3][3] += a.w * w.w;
        }
        __syncthreads();
    }

    float4 bv = *(const float4*)&bias[c0 + tc];
#pragma unroll
    for (int i2 = 0; i2 < 4; ++i2) {
        int gr = r0 + tr + i2;
        if (gr < Nrows) {
            float4 o;
            o.x = acc[i2][0] + bv.x;
            o.y = acc[i2][1] + bv.y;
            o.z = acc[i2][2] + bv.z;
            o.w = acc[i2][3] + bv.w;
            *(float4*)&Y[(size_t)gr * 256 + c0 + tc] = o;
        }
    }
}

// ---- BN ----
__global__ void colstats(const float* __restrict__ Y, float* __restrict__ stats, int Nrows) {
    int c = threadIdx.x;
    int r0 = blockIdx.x * 256;
    int rend = min(r0 + 256, Nrows);
    float s = 0.f, sq = 0.f;
    for (int r = r0; r < rend; ++r) {
        float v = Y[(size_t)r * 256 + c];
        s += v;
        sq += v * v;
    }
    atomicAdd(&stats[c], s);
    atomicAdd(&stats[256 + c], sq);
}

__global__ void bnparams(const float* __restrict__ stats, const float* __restrict__ g,
                         const float* __restrict__ bt, float* __restrict__ params, float invN) {
    int c = threadIdx.x;
    float mean = stats[c] * invN;
    float var = stats[256 + c] * invN - mean * mean;
    float scale = g[c] * rsqrtf(var + 1e-5f);
    params[c] = scale;
    params[256 + c] = bt[c] - mean * scale;
}

__global__ void bn_apply(const float4* __restrict__ Y, const float* __restrict__ params,
                         float4* __restrict__ out, int total4, int relu) {
    int i = blockIdx.x * blockDim.x + threadIdx.x;
    if (i >= total4) return;
    int cq = i & 63;
    float4 sc = ((const float4*)params)[cq];
    float4 sh = ((const float4*)(params + 256))[cq];
    float4 y = Y[i];
    float4 o;
    o.x = y.x * sc.x + sh.x;
    o.y = y.y * sc.y + sh.y;
    o.z = y.z * sc.z + sh.z;
    o.w = y.w * sc.w + sh.w;
    if (relu) {
        o.x = fmaxf(o.x, 0.f);
        o.y = fmaxf(o.y, 0.f);
        o.z = fmaxf(o.z, 0.f);
        o.w = fmaxf(o.w, 0.f);
    }
    out[i] = o;
}

extern "C" void kernel_launch(void* const* d_in, const int* in_sizes, int n_in,
                              void* d_out, int out_size, void* d_ws, size_t ws_size,
                              hipStream_t stream) {
    const float* x      = (const float*)d_in[0];
    const int*   ei     = (const int*)d_in[1];
    const float* eps    = (const float*)d_in[2];
    const float* W1_0   = (const float*)d_in[3];
    const float* W1rest = (const float*)d_in[4];
    const float* b1     = (const float*)d_in[5];
    const float* g1     = (const float*)d_in[6];
    const float* bt1    = (const float*)d_in[7];
    const float* W2     = (const float*)d_in[8];
    const float* b2     = (const float*)d_in[9];
    const float* g2     = (const float*)d_in[10];
    const float* bt2    = (const float*)d_in[11];

    const int N = in_sizes[0] / 128;
    const int E = in_sizes[1] / 2;
    const int* row = ei;
    const int* col = ei + E;

    float* out  = (float*)d_out;
    float* bufA = (float*)d_ws;              // N x 256
    float* bufY = bufA + (size_t)N * 256;    // N x 256
    float* stats  = bufY + (size_t)N * 256;  // 6*512
    float* params = stats + 6 * 512;         // 6*512
    int* deg    = (int*)(params + 6 * 512);  // N
    int* cursor = deg + N;                   // N
    int* rowptr = cursor + N;                // N+1
    int* bs     = rowptr + N + 1;            // 256
    int* bo     = bs + 256;                  // 256
    int* idx    = bo + 256;                  // E

    const float invN = 1.f / (float)N;
    const int B = (N + 255) / 256;  // scan blocks (196 for N=50000, must be <= 256)

    // ---- CSR build (once per call) ----
    zero_i<<<(N + 255) / 256, 256, 0, stream>>>(deg, N);
    hist_k<<<(E + 255) / 256, 256, 0, stream>>>(row, deg, E);
    block_sums<<<B, 256, 0, stream>>>(deg, bs, N);
    scan_bs<<<1, 256, 0, stream>>>(bs, bo, B);
    finalize_rowptr<<<B, 256, 0, stream>>>(deg, bo, rowptr, cursor, N, E);
    fill_csr<<<(E + 255) / 256, 256, 0, stream>>>(row, col, cursor, idx, E);

    zero_f<<<(6 * 512 + 255) / 256, 256, 0, stream>>>(stats, 6 * 512);

    const float* h = x;
    for (int layer = 0; layer < 3; ++layer) {
        const int Hin = (layer == 0) ? 128 : 256;
        const int total4 = N * 256 / 4;

        // bufA = (1+eps)*h + neighbor sum (pull, no atomics)
        if (Hin == 128)
            aggregate<128><<<(N + 3) / 4, 256, 0, stream>>>(h, rowptr, idx, eps, layer, bufA, N);
        else
            aggregate<256><<<(N + 3) / 4, 256, 0, stream>>>(h, rowptr, idx, eps, layer, bufA, N);

        // Linear 1
        const float* Wa = (layer == 0) ? W1_0 : (W1rest + (size_t)(layer - 1) * 256 * 256);
        dim3 gg((N + 63) / 64, 4);
        if (Hin == 128)
            gemm_bias<128><<<gg, 256, 0, stream>>>(bufA, Wa, b1 + layer * 256, bufY, N);
        else
            gemm_bias<256><<<gg, 256, 0, stream>>>(bufA, Wa, b1 + layer * 256, bufY, N);

        // BN 1 + ReLU -> bufA
        float* st1 = stats + layer * 1024;
        float* pr1 = params + layer * 1024;
        colstats<<<(N + 255) / 256, 256, 0, stream>>>(bufY, st1, N);
        bnparams<<<1, 256, 0, stream>>>(st1, g1 + layer * 256, bt1 + layer * 256, pr1, invN);
        bn_apply<<<(total4 + 255) / 256, 256, 0, stream>>>(
            (const float4*)bufY, pr1, (float4*)bufA, total4, 1);

        // Linear 2
        gemm_bias<256><<<gg, 256, 0, stream>>>(bufA, W2 + (size_t)layer * 256 * 256,
                                               b2 + layer * 256, bufY, N);

        // BN 2 (+ inter-layer ReLU) -> out
        float* st2 = st1 + 512;
        float* pr2 = pr1 + 512;
        colstats<<<(N + 255) / 256, 256, 0, stream>>>(bufY, st2, N);
        bnparams<<<1, 256, 0, stream>>>(st2, g2 + layer * 256, bt2 + layer * 256, pr2, invN);
        bn_apply<<<(total4 + 255) / 256, 256, 0, stream>>>(
            (const float4*)bufY, pr2, (float4*)out, total4, (layer < 2) ? 1 : 0);

        h = out;
    }
}

// Round 3
// 569.768 us; speedup vs baseline: 13.5622x; 2.4932x over previous
//
#include <hip/hip_runtime.h>
#include <hip/hip_bf16.h>
#include <math.h>
#include <stdint.h>

typedef short short8 __attribute__((ext_vector_type(8)));
typedef float f32x4 __attribute__((ext_vector_type(4)));

__device__ __forceinline__ float bf2f(unsigned int u) {
    union { unsigned int i; float f; } x; x.i = u << 16; return x.f;
}
__device__ __forceinline__ unsigned short f2bf(float f) {
    union { float f; unsigned int i; } x; x.f = f;
    unsigned int r = x.i + 0x7fffu + ((x.i >> 16) & 1u);
    return (unsigned short)(r >> 16);
}

// ---------------- CSR build ----------------
__global__ void zero_i(int* __restrict__ p, int n) {
    int i = blockIdx.x * blockDim.x + threadIdx.x;
    if (i < n) p[i] = 0;
}
__global__ void hist_k(const int* __restrict__ row, int* __restrict__ deg, int E) {
    int e = blockIdx.x * blockDim.x + threadIdx.x;
    if (e < E) atomicAdd(&deg[row[e]], 1);
}
__global__ void block_sums(const int* __restrict__ deg, int* __restrict__ bs, int N) {
    __shared__ int tmp[256];
    int t = threadIdx.x;
    int i = blockIdx.x * 256 + t;
    tmp[t] = (i < N) ? deg[i] : 0;
    __syncthreads();
    for (int off = 128; off > 0; off >>= 1) {
        if (t < off) tmp[t] += tmp[t + off];
        __syncthreads();
    }
    if (t == 0) bs[blockIdx.x] = tmp[0];
}
__global__ void scan_bs(const int* __restrict__ bs, int* __restrict__ bo, int B) {
    __shared__ int tmp[256];
    int t = threadIdx.x;
    int v = (t < B) ? bs[t] : 0;
    tmp[t] = v;
    __syncthreads();
    for (int off = 1; off < 256; off <<= 1) {
        int x = (t >= off) ? tmp[t - off] : 0;
        __syncthreads();
        tmp[t] += x;
        __syncthreads();
    }
    bo[t] = tmp[t] - v;
}
__global__ void finalize_rowptr(const int* __restrict__ deg, const int* __restrict__ bo,
                                int* __restrict__ rowptr, int* __restrict__ cursor,
                                int N, int E) {
    __shared__ int tmp[256];
    int t = threadIdx.x;
    int i = blockIdx.x * 256 + t;
    int v = (i < N) ? deg[i] : 0;
    tmp[t] = v;
    __syncthreads();
    for (int off = 1; off < 256; off <<= 1) {
        int x = (t >= off) ? tmp[t - off] : 0;
        __syncthreads();
        tmp[t] += x;
        __syncthreads();
    }
    int excl = tmp[t] - v + bo[blockIdx.x];
    if (i < N) { rowptr[i] = excl; cursor[i] = excl; }
    if (i == N) rowptr[N] = E;
}
__global__ void fill_csr(const int* __restrict__ row, const int* __restrict__ col,
                         int* __restrict__ cursor, int* __restrict__ idx, int E) {
    int e = blockIdx.x * blockDim.x + threadIdx.x;
    if (e < E) {
        int p = atomicAdd(&cursor[row[e]], 1);
        idx[p] = col[e];
    }
}

// ---------------- misc prep ----------------
__global__ void zero3(uint4* a, int na, uint4* b, int nb, uint4* c, int nc) {
    int i = blockIdx.x * blockDim.x + threadIdx.x;
    uint4 z = make_uint4(0, 0, 0, 0);
    if (i < na) a[i] = z;
    if (i < nb) b[i] = z;
    if (i < nc) c[i] = z;
}

__global__ void conv_x(const float* __restrict__ x, unsigned short* __restrict__ xb, int total4) {
    int i = blockIdx.x * blockDim.x + threadIdx.x;
    if (i >= total4) return;
    float4 v = *(const float4*)(x + (size_t)i * 4);
    unsigned int lo = (unsigned int)f2bf(v.x) | ((unsigned int)f2bf(v.y) << 16);
    unsigned int hi = (unsigned int)f2bf(v.z) | ((unsigned int)f2bf(v.w) << 16);
    *(uint2*)(xb + (size_t)i * 4) = make_uint2(lo, hi);
}

// transpose+convert all 6 weight matrices into wt (bf16, [cols][K] layout)
__global__ void prep_weights(const float* __restrict__ W1_0, const float* __restrict__ W1rest,
                             const float* __restrict__ W2, unsigned short* __restrict__ wt) {
    int id = blockIdx.x * blockDim.x + threadIdx.x;
    if (id < 32768) {                       // W1_0 [128][256] -> [256][128]
        int k = id >> 8, c = id & 255;
        wt[c * 128 + k] = f2bf(W1_0[id]);
    } else if (id < 163840) {               // W1rest 2x [256][256]
        int t = id - 32768;
        int m = t >> 16, r = t & 65535;
        int k = r >> 8, c = r & 255;
        wt[32768 + m * 65536 + c * 256 + k] = f2bf(W1rest[t]);
    } else if (id < 360448) {               // W2 3x [256][256]
        int t = id - 163840;
        int m = t >> 16, r = t & 65535;
        int k = r >> 8, c = r & 255;
        wt[163840 + m * 65536 + c * 256 + k] = f2bf(W2[t]);
    }
}

// ---------------- aggregation (bf16 in/out, fp32 accum) ----------------
template<int H>
__global__ __launch_bounds__(256) void aggregate_b(const unsigned short* __restrict__ h,
                                                   const int* __restrict__ rowptr,
                                                   const int* __restrict__ idx,
                                                   const float* __restrict__ eps, int layer,
                                                   unsigned short* __restrict__ out, int N) {
    constexpr int NW = H / 128;  // uints (bf16 pairs) per lane
    int lane = threadIdx.x & 63;
    int v = blockIdx.x * 4 + (threadIdx.x >> 6);
    if (v >= N) return;
    float s = 1.f + eps[layer];
    const unsigned int* hu = (const unsigned int*)h;
    float acc[2 * NW];
    {
        const unsigned int* hv = hu + (size_t)v * (H / 2) + lane * NW;
#pragma unroll
        for (int j = 0; j < NW; ++j) {
            unsigned int r = hv[j];
            acc[2 * j]     = s * bf2f(r & 0xffffu);
            acc[2 * j + 1] = s * bf2f(r >> 16);
        }
    }
    int e = rowptr[v], end = rowptr[v + 1];
    for (; e + 3 < end; e += 4) {
        int u0 = idx[e], u1 = idx[e + 1], u2 = idx[e + 2], u3 = idx[e + 3];
        const unsigned int* q0 = hu + (size_t)u0 * (H / 2) + lane * NW;
        const unsigned int* q1 = hu + (size_t)u1 * (H / 2) + lane * NW;
        const unsigned int* q2 = hu + (size_t)u2 * (H / 2) + lane * NW;
        const unsigned int* q3 = hu + (size_t)u3 * (H / 2) + lane * NW;
        unsigned int r0[NW], r1[NW], r2[NW], r3[NW];
#pragma unroll
        for (int j = 0; j < NW; ++j) { r0[j] = q0[j]; r1[j] = q1[j]; r2[j] = q2[j]; r3[j] = q3[j]; }
#pragma unroll
        for (int j = 0; j < NW; ++j) {
            acc[2 * j]     += (bf2f(r0[j] & 0xffffu) + bf2f(r1[j] & 0xffffu)) +
                              (bf2f(r2[j] & 0xffffu) + bf2f(r3[j] & 0xffffu));
            acc[2 * j + 1] += (bf2f(r0[j] >> 16) + bf2f(r1[j] >> 16)) +
                              (bf2f(r2[j] >> 16) + bf2f(r3[j] >> 16));
        }
    }
    for (; e < end; ++e) {
        int u = idx[e];
        const unsigned int* q = hu + (size_t)u * (H / 2) + lane * NW;
#pragma unroll
        for (int j = 0; j < NW; ++j) {
            unsigned int r = q[j];
            acc[2 * j]     += bf2f(r & 0xffffu);
            acc[2 * j + 1] += bf2f(r >> 16);
        }
    }
    unsigned int* op = (unsigned int*)out + (size_t)v * (H / 2) + lane * NW;
#pragma unroll
    for (int j = 0; j < NW; ++j)
        op[j] = (unsigned int)f2bf(acc[2 * j]) | ((unsigned int)f2bf(acc[2 * j + 1]) << 16);
}

// ---------------- bf16 MFMA GEMM + bias + BN column stats ----------------
// Y[N x 256] = A[Npad x K] @ W[K x 256] (+bias); W given transposed: Wt[256][K].
// Tile 128x128, BK=32, 4 waves (2x2), each wave 64x64 via 4x4 16x16x32 MFMAs.
template<int K>
__global__ __launch_bounds__(256) void gemm_mfma(const unsigned short* __restrict__ A,
                                                 const unsigned short* __restrict__ Wt,
                                                 const float* __restrict__ bias,
                                                 unsigned short* __restrict__ Y,
                                                 float* __restrict__ stats,
                                                 int Nrows) {
    __shared__ unsigned short sA[2][128 * 32];
    __shared__ unsigned short sB[2][128 * 32];
    const int tid = threadIdx.x;
    const int lane = tid & 63;
    const int wid = tid >> 6;
    const int wm = wid >> 1, wn = wid & 1;
    const int r0 = blockIdx.x * 128;
    const int c0 = blockIdx.y * 128;
    const int chunk0 = wid * 2;

    f32x4 acc[4][4] = {};  // [i(m)][n]

    auto stage = [&](int buf, int k0) {
#pragma unroll
        for (int q = 0; q < 2; ++q) {
            int chunk = chunk0 + q;
            int byteoff = chunk * 1024 + lane * 16;
            int row = byteoff >> 6;          // 64B per LDS row (32 bf16)
            int kk = (byteoff & 63) >> 1;    // bf16 index within row
            const unsigned short* gA = A + (size_t)(r0 + row) * K + k0 + kk;
            const unsigned short* gB = Wt + (size_t)(c0 + row) * K + k0 + kk;
            __builtin_amdgcn_global_load_lds(
                (const __attribute__((address_space(1))) void*)(uintptr_t)gA,
                (__attribute__((address_space(3))) void*)(uintptr_t)(&sA[buf][chunk * 512]),
                16, 0, 0);
            __builtin_amdgcn_global_load_lds(
                (const __attribute__((address_space(1))) void*)(uintptr_t)gB,
                (__attribute__((address_space(3))) void*)(uintptr_t)(&sB[buf][chunk * 512]),
                16, 0, 0);
        }
    };

    const int nt = K / 32;
    stage(0, 0);
    const int krow = lane >> 4;   // 0..3 -> k-subgroup of 8
    const int rl = lane & 15;

    for (int t = 0; t < nt; ++t) {
        __syncthreads();                       // stage(t) complete (barrier drains vmcnt)
        if (t + 1 < nt) stage((t + 1) & 1, (t + 1) * 32);   // prefetch next tile
        const unsigned short* sAb = sA[t & 1];
        const unsigned short* sBb = sB[t & 1];
        short8 a[4], b[4];
#pragma unroll
        for (int i = 0; i < 4; ++i) {
            a[i] = *(const short8*)(sAb + (wm * 64 + i * 16 + rl) * 32 + krow * 8);
            b[i] = *(const short8*)(sBb + (wn * 64 + i * 16 + rl) * 32 + krow * 8);
        }
#pragma unroll
        for (int i = 0; i < 4; ++i)
#pragma unroll
            for (int n = 0; n < 4; ++n)
                asm volatile("v_mfma_f32_16x16x32_bf16 %0, %1, %2, %0"
                             : "+v"(acc[i][n])
                             : "v"(a[i]), "v"(b[n]));
    }
    // cover MFMA -> VALU read hazard for the inline-asm MFMAs
    asm volatile("s_nop 7\n\ts_nop 7" ::);

    const int rg = lane >> 4;
#pragma unroll
    for (int n = 0; n < 4; ++n) {
        int col = c0 + wn * 64 + n * 16 + rl;
        float bv = bias[col];
        float s = 0.f, q2 = 0.f;
#pragma unroll
        for (int i = 0; i < 4; ++i) {
#pragma unroll
            for (int r = 0; r < 4; ++r) {
                int grow = r0 + wm * 64 + i * 16 + rg * 4 + r;
                if (grow < Nrows) {
                    float v = acc[i][n][r] + bv;
                    Y[(size_t)grow * 256 + col] = f2bf(v);
                    s += v;
                    q2 += v * v;
                }
            }
        }
        s  += __shfl_xor(s, 16, 64);  s  += __shfl_xor(s, 32, 64);
        q2 += __shfl_xor(q2, 16, 64); q2 += __shfl_xor(q2, 32, 64);
        if (rg == 0) {
            atomicAdd(&stats[col], s);
            atomicAdd(&stats[256 + col], q2);
        }
    }
}

// ---------------- fused BN params + apply (+optional ReLU), bf16 or fp32 out ----------------
__global__ void bn_fuse(const unsigned short* __restrict__ Y, const float* __restrict__ stats,
                        const float* __restrict__ g, const float* __restrict__ bt,
                        float invN, unsigned short* __restrict__ outb, float* __restrict__ outf,
                        int total8, int relu) {
    int i = blockIdx.x * blockDim.x + threadIdx.x;
    if (i >= total8) return;
    int col0 = (i & 31) << 3;
    uint4 y = ((const uint4*)Y)[i];
    unsigned int yy[4] = {y.x, y.y, y.z, y.w};
    float o[8];
#pragma unroll
    for (int j = 0; j < 4; ++j) {
        o[2 * j]     = bf2f(yy[j] & 0xffffu);
        o[2 * j + 1] = bf2f(yy[j] >> 16);
    }
#pragma unroll
    for (int j = 0; j < 8; ++j) {
        int c = col0 + j;
        float mean = stats[c] * invN;
        float var = stats[256 + c] * invN - mean * mean;
        float sc = g[c] * rsqrtf(var + 1e-5f);
        float sh = bt[c] - mean * sc;
        float v = o[j] * sc + sh;
        if (relu) v = fmaxf(v, 0.f);
        o[j] = v;
    }
    if (outf) {
        float4* of = (float4*)outf;
        of[2 * i]     = make_float4(o[0], o[1], o[2], o[3]);
        of[2 * i + 1] = make_float4(o[4], o[5], o[6], o[7]);
    } else {
        uint4 w;
        w.x = (unsigned int)f2bf(o[0]) | ((unsigned int)f2bf(o[1]) << 16);
        w.y = (unsigned int)f2bf(o[2]) | ((unsigned int)f2bf(o[3]) << 16);
        w.z = (unsigned int)f2bf(o[4]) | ((unsigned int)f2bf(o[5]) << 16);
        w.w = (unsigned int)f2bf(o[6]) | ((unsigned int)f2bf(o[7]) << 16);
        ((uint4*)outb)[i] = w;
    }
}

extern "C" void kernel_launch(void* const* d_in, const int* in_sizes, int n_in,
                              void* d_out, int out_size, void* d_ws, size_t ws_size,
                              hipStream_t stream) {
    const float* x      = (const float*)d_in[0];
    const int*   ei     = (const int*)d_in[1];
    const float* eps    = (const float*)d_in[2];
    const float* W1_0   = (const float*)d_in[3];
    const float* W1rest = (const float*)d_in[4];
    const float* b1     = (const float*)d_in[5];
    const float* g1     = (const float*)d_in[6];
    const float* bt1    = (const float*)d_in[7];
    const float* W2     = (const float*)d_in[8];
    const float* b2     = (const float*)d_in[9];
    const float* g2     = (const float*)d_in[10];
    const float* bt2    = (const float*)d_in[11];

    const int N = in_sizes[0] / 128;
    const int E = in_sizes[1] / 2;
    const int* row = ei;
    const int* col = ei + E;
    const int Npad = ((N + 127) / 128) * 128;
    const int nbRow = Npad / 128;

    char* w = (char*)d_ws;
    auto alloc = [&](size_t bytes) {
        char* p = w;
        w += (bytes + 255) & ~(size_t)255;
        return p;
    };
    unsigned short* xb = (unsigned short*)alloc((size_t)Npad * 128 * 2);
    unsigned short* p0 = (unsigned short*)alloc((size_t)Npad * 256 * 2);
    unsigned short* p1 = (unsigned short*)alloc((size_t)Npad * 256 * 2);
    unsigned short* Yb = (unsigned short*)alloc((size_t)Npad * 256 * 2);
    unsigned short* wt = (unsigned short*)alloc((size_t)360448 * 2);
    float* stats = (float*)alloc(3072 * 4);
    int* deg    = (int*)alloc((size_t)N * 4);
    int* cursor = (int*)alloc((size_t)N * 4);
    int* rowptr = (int*)alloc((size_t)(N + 1) * 4);
    int* bs     = (int*)alloc(256 * 4);
    int* bo     = (int*)alloc(256 * 4);
    int* idxb   = (int*)alloc((size_t)E * 4);

    const float invN = 1.f / (float)N;
    const int B = (N + 255) / 256;

    // CSR build
    zero_i<<<(N + 255) / 256, 256, 0, stream>>>(deg, N);
    hist_k<<<(E + 255) / 256, 256, 0, stream>>>(row, deg, E);
    block_sums<<<B, 256, 0, stream>>>(deg, bs, N);
    scan_bs<<<1, 256, 0, stream>>>(bs, bo, B);
    finalize_rowptr<<<B, 256, 0, stream>>>(deg, bo, rowptr, cursor, N, E);
    fill_csr<<<(E + 255) / 256, 256, 0, stream>>>(row, col, cursor, idxb, E);

    // zero: p0 tail, p1 tail, stats
    int tail16 = (Npad - N) * 256 * 2 / 16;  // uint4 count per tail
    {
        uint4* t0 = (uint4*)(p0 + (size_t)N * 256);
        uint4* t1 = (uint4*)(p1 + (size_t)N * 256);
        int mx = tail16 > 768 ? tail16 : 768;
        zero3<<<(mx + 255) / 256, 256, 0, stream>>>(t0, tail16, t1, tail16, (uint4*)stats, 768);
    }

    conv_x<<<(N * 32 + 255) / 256, 256, 0, stream>>>(x, xb, N * 32);
    prep_weights<<<(360448 + 255) / 256, 256, 0, stream>>>(W1_0, W1rest, W2, wt);

    const int aggGrid = (N + 3) / 4;
    const int bnGrid = (N * 32 + 255) / 256;
    dim3 gg(nbRow, 2);

    for (int layer = 0; layer < 3; ++layer) {
        float* st = stats + layer * 1024;
        // aggregation -> p0
        if (layer == 0)
            aggregate_b<128><<<aggGrid, 256, 0, stream>>>(xb, rowptr, idxb, eps, 0, p0, N);
        else
            aggregate_b<256><<<aggGrid, 256, 0, stream>>>(p1, rowptr, idxb, eps, layer, p0, N);

        // Linear1 + stats
        if (layer == 0)
            gemm_mfma<128><<<gg, 256, 0, stream>>>(p0, wt, b1, Yb, st, N);
        else
            gemm_mfma<256><<<gg, 256, 0, stream>>>(p0, wt + 32768 + (size_t)(layer - 1) * 65536,
                                                   b1 + layer * 256, Yb, st, N);
        // BN1 + ReLU -> p0 (bf16)
        bn_fuse<<<bnGrid, 256, 0, stream>>>(Yb, st, g1 + layer * 256, bt1 + layer * 256,
                                            invN, p0, nullptr, N * 32, 1);
        // Linear2 + stats
        gemm_mfma<256><<<gg, 256, 0, stream>>>(p0, wt + 163840 + (size_t)layer * 65536,
                                               b2 + layer * 256, Yb, st + 512, N);
        // BN2 (+ReLU for layers 0,1) -> p1 bf16, or fp32 d_out for final
        if (layer < 2)
            bn_fuse<<<bnGrid, 256, 0, stream>>>(Yb, st + 512, g2 + layer * 256, bt2 + layer * 256,
                                                invN, p1, nullptr, N * 32, 1);
        else
            bn_fuse<<<bnGrid, 256, 0, stream>>>(Yb, st + 512, g2 + layer * 256, bt2 + layer * 256,
                                                invN, nullptr, (float*)d_out, N * 32, 0);
    }
}